// Round 3
// baseline (871.022 us; speedup 1.0000x reference)
//
#include <hip/hip_runtime.h>

#define DI __device__ __forceinline__

typedef __attribute__((ext_vector_type(8))) short short8;
typedef __attribute__((ext_vector_type(4))) float floatx4;
typedef unsigned short u16;

// ---- constants ----
#define Bb 2
#define Tt 2048
#define Cc 1024
#define Hh 16
#define Dd 64
// base-2 softmax: s2 = (q.k) * (1/sqrt(64)) * log2(e)
#define C1 0.1803368801111244f
#define NEGBIG (-1e30f)

DI float bf2f(u16 u) { union { unsigned int i; float f; } v; v.i = ((unsigned int)u) << 16; return v.f; }
DI u16 f2bf(float f) {
  union { float f; unsigned int i; } v; v.f = f;
  unsigned int i = v.i;
  unsigned int r = i + 0x7fffu + ((i >> 16) & 1u);  // RNE
  return (u16)(r >> 16);
}

DI floatx4 mfma16(short8 a, short8 b, floatx4 c) {
  return __builtin_amdgcn_mfma_f32_16x16x32_bf16(a, b, c, 0, 0, 0);
}

// load 8 consecutive elements (element offset eoff) as 8 bf16 packed in uint4
DI uint4 load8(const void* p, size_t eoff, int isbf) {
  if (isbf) {
    return *(const uint4*)((const u16*)p + eoff);
  } else {
    const float* f = (const float*)p + eoff;
    float4 a = *(const float4*)f;
    float4 b = *(const float4*)(f + 4);
    union { uint4 u; u16 s[8]; } r;
    r.s[0] = f2bf(a.x); r.s[1] = f2bf(a.y); r.s[2] = f2bf(a.z); r.s[3] = f2bf(a.w);
    r.s[4] = f2bf(b.x); r.s[5] = f2bf(b.y); r.s[6] = f2bf(b.z); r.s[7] = f2bf(b.w);
    return r.u;
  }
}

DI float loadb(const void* p, int i, int isbf) {
  return isbf ? bf2f(((const u16*)p)[i]) : ((const float*)p)[i];
}

// ============================================================
// dtype detector (inputs only): sample even u16 indices of x.
// ============================================================
__global__ void detect_dtype(const u16* __restrict__ x, int* __restrict__ flag) {
  __shared__ int cnt[256];
  int c = 0;
  for (int i = threadIdx.x; i < 4096; i += 256) {
    unsigned u = x[2 * i];
    unsigned e = (u >> 7) & 0xFFu;
    c += (e == 0u || (e >= 100u && e <= 150u)) ? 1 : 0;
  }
  cnt[threadIdx.x] = c;
  __syncthreads();
  for (int s = 128; s > 0; s >>= 1) {
    if ((int)threadIdx.x < s) cnt[threadIdx.x] += cnt[threadIdx.x + s];
    __syncthreads();
  }
  if (threadIdx.x == 0) *flag = (cnt[0] > 2458) ? 1 : 0;
}

// ============================================================
// GEMM-BT: Out[m,n] = sum_k A[m,k] * W[n,k] + bias[n]
// 128x128 tile, BK=32, 256 threads = 4 waves (2x2 of 64x64)
// ============================================================
__global__ __launch_bounds__(256) void qkv_gemm(
    const void* __restrict__ X,
    const void* __restrict__ Wq, const void* __restrict__ Wk, const void* __restrict__ Wv,
    const void* __restrict__ bq, const void* __restrict__ bk, const void* __restrict__ bv,
    u16* __restrict__ Qb, u16* __restrict__ Kb, u16* __restrict__ Vb,
    const int* __restrict__ flagp) {
  __shared__ __align__(16) u16 As[128 * 40];
  __shared__ __align__(16) u16 Bs[128 * 40];
  const int isbf = *flagp;
  const int z = blockIdx.z;
  const void* W = (z == 0) ? Wq : (z == 1) ? Wk : Wv;
  const void* bias = (z == 0) ? bq : (z == 1) ? bk : bv;
  u16* Out = (z == 0) ? Qb : (z == 1) ? Kb : Vb;

  const int m0 = blockIdx.y * 128, n0 = blockIdx.x * 128;
  const int tid = threadIdx.x;
  const int w = tid >> 6, lane = tid & 63, quad = lane >> 4, l15 = lane & 15;
  const int wm = w >> 1, wn = w & 1;

  floatx4 acc[4][4];
#pragma unroll
  for (int a = 0; a < 4; ++a)
#pragma unroll
    for (int b2 = 0; b2 < 4; ++b2) acc[a][b2] = (floatx4){0.f, 0.f, 0.f, 0.f};

  for (int k0 = 0; k0 < Cc; k0 += 32) {
    __syncthreads();
#pragma unroll
    for (int i = 0; i < 2; ++i) {
      int slot = tid + i * 256;  // 512 slots = 128 rows x 4 (8-elem groups)
      int row = slot >> 2, c8 = slot & 3;
      *(uint4*)(As + row * 40 + c8 * 8) = load8(X, (size_t)(m0 + row) * Cc + k0 + c8 * 8, isbf);
      *(uint4*)(Bs + row * 40 + c8 * 8) = load8(W, (size_t)(n0 + row) * Cc + k0 + c8 * 8, isbf);
    }
    __syncthreads();
    short8 af[4], bfv[4];
#pragma unroll
    for (int t = 0; t < 4; ++t)
      af[t] = *(const short8*)(As + (wm * 64 + t * 16 + l15) * 40 + quad * 8);
#pragma unroll
    for (int t = 0; t < 4; ++t)
      bfv[t] = *(const short8*)(Bs + (wn * 64 + t * 16 + l15) * 40 + quad * 8);
#pragma unroll
    for (int tm = 0; tm < 4; ++tm)
#pragma unroll
      for (int tn = 0; tn < 4; ++tn) acc[tm][tn] = mfma16(af[tm], bfv[tn], acc[tm][tn]);
  }

  // epilogue: scatter to [B,H,T,D] (bf16 workspace)
  float bb[4];
#pragma unroll
  for (int tn = 0; tn < 4; ++tn) bb[tn] = loadb(bias, n0 + wn * 64 + tn * 16 + l15, isbf);
#pragma unroll
  for (int tm = 0; tm < 4; ++tm) {
#pragma unroll
    for (int tn = 0; tn < 4; ++tn) {
      int n = n0 + wn * 64 + tn * 16 + l15;
      int h = n >> 6, d = n & 63;
#pragma unroll
      for (int r = 0; r < 4; ++r) {
        int m = m0 + wm * 64 + tm * 16 + quad * 4 + r;
        int b = m >> 11, t = m & 2047;
        Out[(((size_t)(b * Hh + h) * Tt) + t) * Dd + d] = f2bf(acc[tm][tn][r] + bb[tn]);
      }
    }
  }
}

// out-proj: fp32 output to d_out
__global__ __launch_bounds__(256) void out_gemm(
    const u16* __restrict__ Y, const void* __restrict__ Wo, const void* __restrict__ bo,
    float* __restrict__ Out, const int* __restrict__ flagp) {
  __shared__ __align__(16) u16 As[128 * 40];
  __shared__ __align__(16) u16 Bs[128 * 40];
  const int isbf = *flagp;
  const int m0 = blockIdx.y * 128, n0 = blockIdx.x * 128;
  const int tid = threadIdx.x;
  const int w = tid >> 6, lane = tid & 63, quad = lane >> 4, l15 = lane & 15;
  const int wm = w >> 1, wn = w & 1;

  floatx4 acc[4][4];
#pragma unroll
  for (int a = 0; a < 4; ++a)
#pragma unroll
    for (int b2 = 0; b2 < 4; ++b2) acc[a][b2] = (floatx4){0.f, 0.f, 0.f, 0.f};

  for (int k0 = 0; k0 < Cc; k0 += 32) {
    __syncthreads();
#pragma unroll
    for (int i = 0; i < 2; ++i) {
      int slot = tid + i * 256;
      int row = slot >> 2, c8 = slot & 3;
      *(uint4*)(As + row * 40 + c8 * 8) = *(const uint4*)(Y + (size_t)(m0 + row) * Cc + k0 + c8 * 8);
      *(uint4*)(Bs + row * 40 + c8 * 8) = load8(Wo, (size_t)(n0 + row) * Cc + k0 + c8 * 8, isbf);
    }
    __syncthreads();
    short8 af[4], bfv[4];
#pragma unroll
    for (int t = 0; t < 4; ++t)
      af[t] = *(const short8*)(As + (wm * 64 + t * 16 + l15) * 40 + quad * 8);
#pragma unroll
    for (int t = 0; t < 4; ++t)
      bfv[t] = *(const short8*)(Bs + (wn * 64 + t * 16 + l15) * 40 + quad * 8);
#pragma unroll
    for (int tm = 0; tm < 4; ++tm)
#pragma unroll
      for (int tn = 0; tn < 4; ++tn) acc[tm][tn] = mfma16(af[tm], bfv[tn], acc[tm][tn]);
  }

  float bb[4];
#pragma unroll
  for (int tn = 0; tn < 4; ++tn) bb[tn] = loadb(bo, n0 + wn * 64 + tn * 16 + l15, isbf);
#pragma unroll
  for (int tm = 0; tm < 4; ++tm)
#pragma unroll
    for (int tn = 0; tn < 4; ++tn) {
      int n = n0 + wn * 64 + tn * 16 + l15;
#pragma unroll
      for (int r = 0; r < 4; ++r) {
        int m = m0 + wm * 64 + tm * 16 + quad * 4 + r;
        Out[(size_t)m * Cc + n] = acc[tm][tn][r] + bb[tn];
      }
    }
}

// ============================================================
// Attention: one WG (256 thr, 4 waves) per (b, h, 16 q-rows).
// att written as FP32 to d_out; y (bf16) to workspace.
// ============================================================
__global__ __launch_bounds__(256) void attn_kernel(
    const u16* __restrict__ Qbuf, const u16* __restrict__ Kbuf, const u16* __restrict__ Vbuf,
    float* __restrict__ Att, u16* __restrict__ Ybuf) {
  __shared__ __align__(16) u16 Qs[16 * 72];
  __shared__ __align__(16) u16 Ks[128 * 72];
  __shared__ __align__(16) u16 Vts[64 * 136];
  __shared__ __align__(16) u16 Ps[16 * 136];
  __shared__ float redM[4][16], redL[4][16];
  __shared__ float Mfin[16], Lfin[16];

  const int qt = blockIdx.x, h = blockIdx.y, b = blockIdx.z;
  const int q0 = qt * 16, q_hi = q0 + 15;
  const int tid = threadIdx.x;
  const int w = tid >> 6, lane = tid & 63, quad = lane >> 4, l15 = lane & 15;

  const size_t headoff = (size_t)(b * Hh + h) * Tt * Dd;
  const u16* Qh = Qbuf + headoff;
  const u16* Kh = Kbuf + headoff;
  const u16* Vh = Vbuf + headoff;
  float* attO = Att + (size_t)(b * Hh + h) * Tt * Tt;

  // stage Q tile [16][64] -> Qs[16][72]
  {
    int row = tid >> 4, c4 = tid & 15;
    *(uint2*)(Qs + row * 72 + c4 * 4) = *(const uint2*)(Qh + (size_t)(q0 + row) * Dd + c4 * 4);
  }
  __syncthreads();
  short8 aq0 = *(const short8*)(Qs + l15 * 72 + quad * 8);
  short8 aq1 = *(const short8*)(Qs + l15 * 72 + 32 + quad * 8);

  float m4[4], l4[4];
#pragma unroll
  for (int r = 0; r < 4; ++r) { m4[r] = NEGBIG; l4[r] = 0.f; }

  const int nact = (q_hi + 1 + 127) / 128;

  // ---------- pass 1: stats ----------
  for (int c = 0; c < nact; ++c) {
    const int kb = c * 128;
    __syncthreads();
#pragma unroll
    for (int i = 0; i < 4; ++i) {
      int slot = tid + i * 256;
      int row = slot >> 3, c8 = slot & 7;
      *(uint4*)(Ks + row * 72 + c8 * 8) = *(const uint4*)(Kh + (size_t)(kb + row) * Dd + c8 * 8);
    }
    __syncthreads();
#pragma unroll
    for (int tile = 0; tile < 2; ++tile) {
      int kloc = w * 32 + tile * 16;
      floatx4 acc = (floatx4){0.f, 0.f, 0.f, 0.f};
      short8 b0 = *(const short8*)(Ks + (kloc + l15) * 72 + quad * 8);
      short8 b1 = *(const short8*)(Ks + (kloc + l15) * 72 + 32 + quad * 8);
      acc = mfma16(aq0, b0, acc);
      acc = mfma16(aq1, b1, acc);
      int key = kb + kloc + l15;
#pragma unroll
      for (int r = 0; r < 4; ++r) {
        int qi = q0 + quad * 4 + r;
        if (key <= qi) {
          float s2 = acc[r] * C1;
          float mo = m4[r];
          float mn = fmaxf(mo, s2);
          l4[r] = l4[r] * exp2f(mo - mn) + exp2f(s2 - mn);
          m4[r] = mn;
        }
      }
    }
  }

  // ---------- merge stats ----------
#pragma unroll
  for (int r = 0; r < 4; ++r) {
    float m = m4[r], l = l4[r];
#pragma unroll
    for (int off = 8; off >= 1; off >>= 1) {
      float mo = __shfl_xor(m, off, 64);
      float lo = __shfl_xor(l, off, 64);
      float mn = fmaxf(m, mo);
      l = l * exp2f(m - mn) + lo * exp2f(mo - mn);
      m = mn;
    }
    m4[r] = m; l4[r] = l;
  }
  if (l15 == 0) {
#pragma unroll
    for (int r = 0; r < 4; ++r) { redM[w][quad * 4 + r] = m4[r]; redL[w][quad * 4 + r] = l4[r]; }
  }
  __syncthreads();
  if (tid < 16) {
    float m = NEGBIG;
#pragma unroll
    for (int w2 = 0; w2 < 4; ++w2) m = fmaxf(m, redM[w2][tid]);
    float l = 0.f;
#pragma unroll
    for (int w2 = 0; w2 < 4; ++w2) l += redL[w2][tid] * exp2f(redM[w2][tid] - m);
    Mfin[tid] = m;
    Lfin[tid] = 1.0f / l;
  }
  __syncthreads();

  // ---------- pass 2: write att (fp32), accumulate y ----------
  floatx4 yacc = (floatx4){0.f, 0.f, 0.f, 0.f};

  for (int c = 0; c < Tt / 128; ++c) {
    const int kb = c * 128;
    if (kb > q_hi) {
      // fully masked: zero-fill att block [16 rows][128 fp32 cols]
      uint4 z; z.x = 0u; z.y = 0u; z.z = 0u; z.w = 0u;
#pragma unroll
      for (int i = 0; i < 2; ++i) {
        int slot = tid + i * 256;        // 512 float4 groups
        int row = slot >> 5, g = slot & 31;
        *(uint4*)(attO + (size_t)(q0 + row) * Tt + kb + g * 4) = z;
      }
      continue;
    }
    __syncthreads();
#pragma unroll
    for (int i = 0; i < 4; ++i) {
      int slot = tid + i * 256;
      int row = slot >> 3, c8 = slot & 7;
      *(uint4*)(Ks + row * 72 + c8 * 8) = *(const uint4*)(Kh + (size_t)(kb + row) * Dd + c8 * 8);
    }
    {
      int row = tid >> 1, cb = (tid & 1) * 32;
      const u16* src = Vh + (size_t)(kb + row) * Dd + cb;
      union { uint4 u; u16 s[8]; } cv;
#pragma unroll
      for (int g = 0; g < 4; ++g) {
        cv.u = *(const uint4*)(src + g * 8);
#pragma unroll
        for (int j = 0; j < 8; ++j) Vts[(cb + g * 8 + j) * 136 + row] = cv.s[j];
      }
    }
    __syncthreads();

#pragma unroll
    for (int tile = 0; tile < 2; ++tile) {
      int kloc = w * 32 + tile * 16;
      floatx4 acc = (floatx4){0.f, 0.f, 0.f, 0.f};
      short8 b0 = *(const short8*)(Ks + (kloc + l15) * 72 + quad * 8);
      short8 b1 = *(const short8*)(Ks + (kloc + l15) * 72 + 32 + quad * 8);
      acc = mfma16(aq0, b0, acc);
      acc = mfma16(aq1, b1, acc);
      int key = kb + kloc + l15;
#pragma unroll
      for (int r = 0; r < 4; ++r) {
        int row = quad * 4 + r;
        int qi = q0 + row;
        float p = 0.f;
        if (key <= qi) p = exp2f(fminf(acc[r] * C1 - Mfin[row], 0.f)) * Lfin[row];
        attO[(size_t)qi * Tt + key] = p;          // fp32 att output
        Ps[row * 136 + kloc + l15] = f2bf(p);     // bf16 for PV MFMA
      }
    }
    __syncthreads();

#pragma unroll
    for (int ks = 0; ks < 4; ++ks) {
      short8 ap = *(const short8*)(Ps + l15 * 136 + ks * 32 + quad * 8);
      short8 bv = *(const short8*)(Vts + (w * 16 + l15) * 136 + ks * 32 + quad * 8);
      yacc = mfma16(ap, bv, yacc);
    }
  }

#pragma unroll
  for (int r = 0; r < 4; ++r) {
    int qi = q0 + quad * 4 + r;
    Ybuf[(size_t)(b * Tt + qi) * Cc + h * Dd + w * 16 + l15] = f2bf(yacc[r]);
  }
}

extern "C" void kernel_launch(void* const* d_in, const int* in_sizes, int n_in,
                              void* d_out, int out_size, void* d_ws, size_t ws_size,
                              hipStream_t stream) {
  const void* x  = d_in[0];
  const void* Wq = d_in[1];
  const void* bq = d_in[2];
  const void* Wk = d_in[3];
  const void* bk = d_in[4];
  const void* Wv = d_in[5];
  const void* bv = d_in[6];
  const void* Wo = d_in[7];
  const void* bo = d_in[8];
  float* out = (float*)d_out;

  char* wsb = (char*)d_ws;
  int* flag = (int*)wsb;                          // 256 B header
  u16* Qb = (u16*)(wsb + 256);                    // [B,H,T,D] 8 MB
  u16* Kb = Qb + (size_t)Bb * Tt * Cc;
  u16* Vb = Kb + (size_t)Bb * Tt * Cc;
  u16* Yb = Vb + (size_t)Bb * Tt * Cc;            // [B*T][C] 8 MB

  hipLaunchKernelGGL(detect_dtype, dim3(1), dim3(256), 0, stream, (const u16*)x, flag);
  hipLaunchKernelGGL(qkv_gemm, dim3(8, 32, 3), dim3(256), 0, stream,
                     x, Wq, Wk, Wv, bq, bk, bv, Qb, Kb, Vb, flag);
  float* attOut = out + (size_t)Bb * Tt * Cc;     // y occupies first B*T*C floats
  hipLaunchKernelGGL(attn_kernel, dim3(Tt / 16, Hh, Bb), dim3(256), 0, stream,
                     Qb, Kb, Vb, attOut, Yb);
  hipLaunchKernelGGL(out_gemm, dim3(8, 32, 1), dim3(256), 0, stream,
                     Yb, Wo, bo, out, flag);
}